// Round 3
// baseline (50.466 us; speedup 1.0000x reference)
//
#include <hip/hip_runtime.h>

#define B 32
#define S 2048
#define D 1280
#define R 50

// One block per (b, r) window, r-major block ordering so consecutive block
// IDs cycle through batches (balances per-CU work: window row-counts vary
// 2x across batches). 320 threads; lane t owns float4 column t (D=1280=320*4).
// L is recomputed per block from the upper half of the mask row (lengths are
// guaranteed >= S/2, so mask[0:S/2] is all ones; only 4 KB read, L2-resident).
// Single pass: sum + sum-of-squares, unrolled x4 for load pipelining.
__global__ __launch_bounds__(320) void window_stats_fused(
    const float* __restrict__ x, const int* __restrict__ mask,
    float* __restrict__ out, int getstd)
{
    const int blk = blockIdx.x;
    const int b = blk & (B - 1);   // r-major: blk = r*B + b
    const int r = blk >> 5;
    const int t = threadIdx.x;     // 0..319

    // ---- L = S/2 + sum(mask[b, S/2:]) ----
    // Upper half = 1024 ints = 256 int4; lanes t<256 load one each.
    const int4* __restrict__ mrow =
        reinterpret_cast<const int4*>(mask + (size_t)b * S + S / 2);
    int lsum = 0;
    if (t < 256) {
        int4 v = mrow[t];
        lsum = v.x + v.y + v.z + v.w;
    }
    #pragma unroll
    for (int off = 32; off > 0; off >>= 1) lsum += __shfl_down(lsum, off, 64);
    __shared__ int wsum[5];
    if ((t & 63) == 0) wsum[t >> 6] = lsum;
    __syncthreads();
    const int L = S / 2 + wsum[0] + wsum[1] + wsum[2] + wsum[3] + wsum[4];

    // ---- window geometry (matches reference exactly) ----
    const int m   = L / R;
    const int gap = L - m * R;
    const int gl  = (gap + 1) >> 1;   // ceil(gap/2) leading windows of size m+1
    const int mid = R - gap;          // middle windows of size m

    int start, cnt;
    if (r < gl) {
        start = r * (m + 1);
        cnt   = m + 1;
    } else if (r < gl + mid) {
        start = gl * (m + 1) + (r - gl) * m;
        cnt   = m;
    } else {
        start = gl * (m + 1) + mid * m + (r - (gl + mid)) * (m + 1);
        cnt   = m + 1;
    }

    const float4* __restrict__ xr =
        reinterpret_cast<const float4*>(x + ((size_t)b * S + (size_t)start) * D) + t;

    // Two independent accumulator chains (A: rows 0,2; B: rows 1,3 of each
    // unrolled group).
    float sA0 = 0.f, sA1 = 0.f, sA2 = 0.f, sA3 = 0.f;
    float qA0 = 0.f, qA1 = 0.f, qA2 = 0.f, qA3 = 0.f;
    float sB0 = 0.f, sB1 = 0.f, sB2 = 0.f, sB3 = 0.f;
    float qB0 = 0.f, qB1 = 0.f, qB2 = 0.f, qB3 = 0.f;

    int i = 0;
    for (; i + 4 <= cnt; i += 4) {
        float4 a = xr[(size_t)(i + 0) * (D / 4)];
        float4 c = xr[(size_t)(i + 1) * (D / 4)];
        float4 d = xr[(size_t)(i + 2) * (D / 4)];
        float4 e = xr[(size_t)(i + 3) * (D / 4)];

        sA0 += a.x; qA0 = fmaf(a.x, a.x, qA0);
        sA1 += a.y; qA1 = fmaf(a.y, a.y, qA1);
        sA2 += a.z; qA2 = fmaf(a.z, a.z, qA2);
        sA3 += a.w; qA3 = fmaf(a.w, a.w, qA3);

        sB0 += c.x; qB0 = fmaf(c.x, c.x, qB0);
        sB1 += c.y; qB1 = fmaf(c.y, c.y, qB1);
        sB2 += c.z; qB2 = fmaf(c.z, c.z, qB2);
        sB3 += c.w; qB3 = fmaf(c.w, c.w, qB3);

        sA0 += d.x; qA0 = fmaf(d.x, d.x, qA0);
        sA1 += d.y; qA1 = fmaf(d.y, d.y, qA1);
        sA2 += d.z; qA2 = fmaf(d.z, d.z, qA2);
        sA3 += d.w; qA3 = fmaf(d.w, d.w, qA3);

        sB0 += e.x; qB0 = fmaf(e.x, e.x, qB0);
        sB1 += e.y; qB1 = fmaf(e.y, e.y, qB1);
        sB2 += e.z; qB2 = fmaf(e.z, e.z, qB2);
        sB3 += e.w; qB3 = fmaf(e.w, e.w, qB3);
    }
    for (; i < cnt; ++i) {
        float4 a = xr[(size_t)i * (D / 4)];
        sA0 += a.x; qA0 = fmaf(a.x, a.x, qA0);
        sA1 += a.y; qA1 = fmaf(a.y, a.y, qA1);
        sA2 += a.z; qA2 = fmaf(a.z, a.z, qA2);
        sA3 += a.w; qA3 = fmaf(a.w, a.w, qA3);
    }

    const float s0 = sA0 + sB0, s1 = sA1 + sB1, s2 = sA2 + sB2, s3 = sA3 + sB3;
    const float q0 = qA0 + qB0, q1 = qA1 + qB1, q2 = qA2 + qB2, q3 = qA3 + qB3;

    const float inv = 1.0f / (float)cnt;
    const float m0 = s0 * inv, m1 = s1 * inv, m2 = s2 * inv, m3 = s3 * inv;

    const size_t obase = ((size_t)b * R + r) * D;
    float4 mv; mv.x = m0; mv.y = m1; mv.z = m2; mv.w = m3;
    reinterpret_cast<float4*>(out + obase)[t] = mv;

    if (getstd) {
        float v0 = fmaxf(fmaf(-m0, m0, q0 * inv), 0.f);
        float v1 = fmaxf(fmaf(-m1, m1, q1 * inv), 0.f);
        float v2 = fmaxf(fmaf(-m2, m2, q2 * inv), 0.f);
        float v3 = fmaxf(fmaf(-m3, m3, q3 * inv), 0.f);
        float4 sv;
        sv.x = sqrtf(v0); sv.y = sqrtf(v1); sv.z = sqrtf(v2); sv.w = sqrtf(v3);
        reinterpret_cast<float4*>(out + (size_t)B * R * D + obase)[t] = sv;
    }
}

extern "C" void kernel_launch(void* const* d_in, const int* in_sizes, int n_in,
                              void* d_out, int out_size, void* d_ws, size_t ws_size,
                              hipStream_t stream)
{
    const float* x    = (const float*)d_in[0];
    const int*   mask = (const int*)d_in[1];
    float*       out  = (float*)d_out;

    const int getstd = (out_size >= 2 * B * R * D) ? 1 : 0;

    window_stats_fused<<<B * R, 320, 0, stream>>>(x, mask, out, getstd);
}

// Round 4
// 48.043 us; speedup vs baseline: 1.0504x; 1.0504x over previous
//
#include <hip/hip_runtime.h>

#define B 32
#define S 2048
#define D 1280
#define R 50

// One single-wave (64-thread) block per (b, r, fifth): each block reduces one
// window over a 256-float column slice (64 float4; lane t owns float4
// f*64 + t of each row). 8000 fine-grained blocks self-balance across CUs
// (previous 5-wave/320-thread blocks left ~8 us of makespan raggedness).
// No LDS / no __syncthreads: mask-length reduction is a wave butterfly.
// Lengths are guaranteed >= S/2, so only the upper half of mask is summed.
// Single pass: sum + sum-of-squares, unrolled x4 for load pipelining.
__global__ __launch_bounds__(64) void window_stats_fine(
    const float* __restrict__ x, const int* __restrict__ mask,
    float* __restrict__ out, int getstd)
{
    const unsigned unit = blockIdx.x;       // 0 .. B*R*5-1
    const unsigned w = unit / 5u;           // window id 0..1599
    const int f = (int)(unit - w * 5u);     // column fifth 0..4
    const int b = (int)(w & (B - 1));       // r-major: w = r*B + b
    const int r = (int)(w >> 5);
    const int t = threadIdx.x;              // 0..63

    // ---- L = S/2 + sum(mask[b, S/2:]) ----  (1024 ints = 256 int4)
    const int4* __restrict__ mrow =
        reinterpret_cast<const int4*>(mask + (size_t)b * S + S / 2);
    int lsum = 0;
    #pragma unroll
    for (int k = 0; k < 4; ++k) {
        int4 v = mrow[t + 64 * k];
        lsum += v.x + v.y + v.z + v.w;
    }
    #pragma unroll
    for (int off = 32; off > 0; off >>= 1) lsum += __shfl_xor(lsum, off, 64);
    const int L = S / 2 + lsum;             // all lanes hold L

    // ---- window geometry (matches reference exactly) ----
    const int m   = L / R;
    const int gap = L - m * R;
    const int gl  = (gap + 1) >> 1;   // ceil(gap/2) leading windows of size m+1
    const int mid = R - gap;          // middle windows of size m

    int start, cnt;
    if (r < gl) {
        start = r * (m + 1);
        cnt   = m + 1;
    } else if (r < gl + mid) {
        start = gl * (m + 1) + (r - gl) * m;
        cnt   = m;
    } else {
        start = gl * (m + 1) + mid * m + (r - (gl + mid)) * (m + 1);
        cnt   = m + 1;
    }

    // lane t reads float4 index f*64 + t of each row; row stride D/4 float4.
    const float4* __restrict__ xr =
        reinterpret_cast<const float4*>(x + ((size_t)b * S + (size_t)start) * D)
        + (f * 64 + t);

    // Two independent accumulator chains for load pipelining.
    float sA0 = 0.f, sA1 = 0.f, sA2 = 0.f, sA3 = 0.f;
    float qA0 = 0.f, qA1 = 0.f, qA2 = 0.f, qA3 = 0.f;
    float sB0 = 0.f, sB1 = 0.f, sB2 = 0.f, sB3 = 0.f;
    float qB0 = 0.f, qB1 = 0.f, qB2 = 0.f, qB3 = 0.f;

    int i = 0;
    for (; i + 4 <= cnt; i += 4) {
        float4 a = xr[(size_t)(i + 0) * (D / 4)];
        float4 c = xr[(size_t)(i + 1) * (D / 4)];
        float4 d = xr[(size_t)(i + 2) * (D / 4)];
        float4 e = xr[(size_t)(i + 3) * (D / 4)];

        sA0 += a.x; qA0 = fmaf(a.x, a.x, qA0);
        sA1 += a.y; qA1 = fmaf(a.y, a.y, qA1);
        sA2 += a.z; qA2 = fmaf(a.z, a.z, qA2);
        sA3 += a.w; qA3 = fmaf(a.w, a.w, qA3);

        sB0 += c.x; qB0 = fmaf(c.x, c.x, qB0);
        sB1 += c.y; qB1 = fmaf(c.y, c.y, qB1);
        sB2 += c.z; qB2 = fmaf(c.z, c.z, qB2);
        sB3 += c.w; qB3 = fmaf(c.w, c.w, qB3);

        sA0 += d.x; qA0 = fmaf(d.x, d.x, qA0);
        sA1 += d.y; qA1 = fmaf(d.y, d.y, qA1);
        sA2 += d.z; qA2 = fmaf(d.z, d.z, qA2);
        sA3 += d.w; qA3 = fmaf(d.w, d.w, qA3);

        sB0 += e.x; qB0 = fmaf(e.x, e.x, qB0);
        sB1 += e.y; qB1 = fmaf(e.y, e.y, qB1);
        sB2 += e.z; qB2 = fmaf(e.z, e.z, qB2);
        sB3 += e.w; qB3 = fmaf(e.w, e.w, qB3);
    }
    for (; i < cnt; ++i) {
        float4 a = xr[(size_t)i * (D / 4)];
        sA0 += a.x; qA0 = fmaf(a.x, a.x, qA0);
        sA1 += a.y; qA1 = fmaf(a.y, a.y, qA1);
        sA2 += a.z; qA2 = fmaf(a.z, a.z, qA2);
        sA3 += a.w; qA3 = fmaf(a.w, a.w, qA3);
    }

    const float s0 = sA0 + sB0, s1 = sA1 + sB1, s2 = sA2 + sB2, s3 = sA3 + sB3;
    const float q0 = qA0 + qB0, q1 = qA1 + qB1, q2 = qA2 + qB2, q3 = qA3 + qB3;

    const float inv = 1.0f / (float)cnt;
    const float m0 = s0 * inv, m1 = s1 * inv, m2 = s2 * inv, m3 = s3 * inv;

    const size_t obase = ((size_t)b * R + r) * D;
    float4 mv; mv.x = m0; mv.y = m1; mv.z = m2; mv.w = m3;
    reinterpret_cast<float4*>(out + obase)[f * 64 + t] = mv;

    if (getstd) {
        float v0 = fmaxf(fmaf(-m0, m0, q0 * inv), 0.f);
        float v1 = fmaxf(fmaf(-m1, m1, q1 * inv), 0.f);
        float v2 = fmaxf(fmaf(-m2, m2, q2 * inv), 0.f);
        float v3 = fmaxf(fmaf(-m3, m3, q3 * inv), 0.f);
        float4 sv;
        sv.x = sqrtf(v0); sv.y = sqrtf(v1); sv.z = sqrtf(v2); sv.w = sqrtf(v3);
        reinterpret_cast<float4*>(out + (size_t)B * R * D + obase)[f * 64 + t] = sv;
    }
}

extern "C" void kernel_launch(void* const* d_in, const int* in_sizes, int n_in,
                              void* d_out, int out_size, void* d_ws, size_t ws_size,
                              hipStream_t stream)
{
    const float* x    = (const float*)d_in[0];
    const int*   mask = (const int*)d_in[1];
    float*       out  = (float*)d_out;

    const int getstd = (out_size >= 2 * B * R * D) ? 1 : 0;

    window_stats_fine<<<B * R * 5, 64, 0, stream>>>(x, mask, out, getstd);
}